// Round 1
// baseline (130.897 us; speedup 1.0000x reference)
//
#include <hip/hip_runtime.h>
#include <math.h>

// BoundaryLoss: out = mean_b mean_{h,w} |sigmoid(logits) - gt| * EDT_bg(gt)
// B=16, H=W=384, single fused kernel, exact early-exit separable EDT.

#define BB 16
#define HH 384
#define WW 384
#define SW 16                    // stripe width (columns per block)
#define NBLK_PER_IMG (WW / SW)   // 24
#define THREADS 256

__global__ __launch_bounds__(THREADS) void boundary_loss_kernel(
    const float* __restrict__ logits, const int* __restrict__ targets,
    float* __restrict__ out) {
  const int blk = blockIdx.x;
  const int b = blk / NBLK_PER_IMG;
  const int j0 = (blk % NBLK_PER_IMG) * SW;
  const int* __restrict__ gt = targets + b * HH * WW;
  const float* __restrict__ lg = logits + b * HH * WW;

  // per-stripe 1D row distances g (u16: g <= 768). 384*16*2 = 12 KB LDS.
  __shared__ unsigned short g_s[HH * SW];

  // ---- Phase 1: exact nearest-fg distance along each row (early-exit) ----
  for (int idx = threadIdx.x; idx < HH * SW; idx += THREADS) {
    const int i = idx >> 4;          // idx / SW
    const int jj = idx & (SW - 1);   // idx % SW
    const int j = j0 + jj;
    const int* __restrict__ row = gt + i * WW;
    int g = HH + WW;                 // BIG = 768 (row with no fg)
    const int rmax = max(j, WW - 1 - j);
    for (int r = 0; r <= rmax; ++r) {
      const int jm = j - r, jp = j + r;
      const bool hit = (jm >= 0 && row[jm] != 0) || (jp < WW && row[jp] != 0);
      if (hit) { g = r; break; }
    }
    g_s[idx] = (unsigned short)g;
  }
  __syncthreads();

  // ---- Phase 2: exact vertical envelope (early-exit: r*r >= best stops) ----
  float acc = 0.0f;
  for (int idx = threadIdx.x; idx < HH * SW; idx += THREADS) {
    const int i = idx >> 4;
    const int jj = idx & (SW - 1);
    const int j = j0 + jj;
    const int g = g_s[idx];
    int best = g * g;
    for (int r = 1; r * r < best; ++r) {
      const int im = i - r, ip = i + r;
      if (im >= 0) { const int v = g_s[im * SW + jj]; best = min(best, r * r + v * v); }
      if (ip < HH) { const int v = g_s[ip * SW + jj]; best = min(best, r * r + v * v); }
    }
    const float dist = sqrtf((float)best);   // all d2 integers < 2^24: exact
    const float x = lg[i * WW + j];
    const float p = 1.0f / (1.0f + expf(-x));
    const float t = (float)gt[i * WW + j];
    acc += fabsf(p - t) * dist;
  }

  // ---- Block reduction: wave shuffle -> LDS -> one atomic per block ----
  __shared__ float red[THREADS / 64];
  for (int off = 32; off > 0; off >>= 1) acc += __shfl_down(acc, off, 64);
  const int lane = threadIdx.x & 63;
  const int wid = threadIdx.x >> 6;
  if (lane == 0) red[wid] = acc;
  __syncthreads();
  if (threadIdx.x == 0) {
    float s = 0.0f;
    for (int w = 0; w < THREADS / 64; ++w) s += red[w];
    atomicAdd(out, s * (1.0f / (float)(BB * HH * WW)));
  }
}

extern "C" void kernel_launch(void* const* d_in, const int* in_sizes, int n_in,
                              void* d_out, int out_size, void* d_ws, size_t ws_size,
                              hipStream_t stream) {
  const float* logits = (const float*)d_in[0];
  const int* targets = (const int*)d_in[1];
  float* out = (float*)d_out;
  // d_out is poisoned 0xAA before every call: zero the accumulator.
  hipMemsetAsync(d_out, 0, sizeof(float), stream);
  boundary_loss_kernel<<<BB * NBLK_PER_IMG, THREADS, 0, stream>>>(logits, targets, out);
}

// Round 2
// 89.878 us; speedup vs baseline: 1.4564x; 1.4564x over previous
//
#include <hip/hip_runtime.h>
#include <math.h>

// BoundaryLoss: out = mean_b mean_{h,w} |sigmoid(logits) - gt| * EDT_bg(gt)
// B=16, H=W=384. Two kernels:
//  1) pack gt!=0 into a bitmask (d_ws) via __ballot
//  2) fused EDT (bitmask clz/ffs row pass in LDS + early-exit column pass) + loss

#define BB 16
#define HH 384
#define WW 384
#define WPR 12                 // u32 words per row = 384/32
#define WPRP 13                // padded LDS stride (13 coprime 32: conflict-free)
#define SW 8                   // stripe width (columns per block)
#define NBLK_PER_IMG (WW / SW) // 48
#define THREADS 256
#define BIGD 768               // H + W

__global__ __launch_bounds__(THREADS) void pack_kernel(
    const int* __restrict__ gt, unsigned* __restrict__ mask) {
  const int idx = blockIdx.x * THREADS + threadIdx.x;  // grid sized exactly
  const bool fg = gt[idx] != 0;
  const unsigned long long m = __ballot(fg);
  const int lane = threadIdx.x & 63;
  if (lane == 0) mask[idx >> 5] = (unsigned)m;
  else if (lane == 32) mask[idx >> 5] = (unsigned)(m >> 32);
}

__global__ __launch_bounds__(THREADS) void boundary_loss_kernel(
    const float* __restrict__ logits, const int* __restrict__ targets,
    const unsigned* __restrict__ mask, float* __restrict__ out) {
  const int blk = blockIdx.x;
  const int b = blk / NBLK_PER_IMG;
  const int j0 = (blk % NBLK_PER_IMG) * SW;
  const int* __restrict__ gt = targets + b * HH * WW;
  const float* __restrict__ lg = logits + b * HH * WW;
  const unsigned* __restrict__ gm = mask + b * HH * WPR;

  __shared__ unsigned m_s[HH * WPRP];        // 384*13*4 = 19968 B
  __shared__ unsigned short g_s[HH * SW];    // 384*8*2  =  6144 B

  // ---- stage the image's fg bitmask into LDS (L2-hot, coalesced) ----
  for (int s = threadIdx.x; s < HH * WPR; s += THREADS) {
    const int row = s / WPR;
    const int w = s - row * WPR;
    m_s[row * WPRP + w] = gm[s];
  }
  __syncthreads();

  // ---- Phase 1: exact nearest-fg distance along each row via clz/ffs ----
  for (int idx = threadIdx.x; idx < HH * SW; idx += THREADS) {
    const int i = idx >> 3;          // / SW
    const int jj = idx & (SW - 1);
    const int j = j0 + jj;
    const unsigned* __restrict__ mr = m_s + i * WPRP;
    const int w = j >> 5, bpos = j & 31;
    const unsigned cur = mr[w];
    // left: set bits at positions <= bpos in word w, else walk left
    const unsigned lm = cur & (0xFFFFFFFFu >> (31 - bpos));
    int dl = BIGD;
    if (lm) {
      dl = bpos - (31 - __clz(lm));
    } else {
      for (int ww = w - 1; ww >= 0; --ww) {
        const unsigned x = mr[ww];
        if (x) { dl = j - (ww * 32 + 31 - __clz(x)); break; }
      }
    }
    // right: set bits at positions >= bpos in word w, else walk right
    const unsigned rm = cur & (0xFFFFFFFFu << bpos);
    int dr = BIGD;
    if (rm) {
      dr = (__ffs(rm) - 1) - bpos;
    } else {
      for (int ww = w + 1; ww < WPR; ++ww) {
        const unsigned x = mr[ww];
        if (x) { dr = ww * 32 + (__ffs(x) - 1) - j; break; }
      }
    }
    g_s[idx] = (unsigned short)min(min(dl, dr), BIGD);
  }
  __syncthreads();

  // ---- Phase 2: exact vertical envelope (early exit: r*r >= best) + loss ----
  float acc = 0.0f;
  for (int idx = threadIdx.x; idx < HH * SW; idx += THREADS) {
    const int i = idx >> 3;
    const int jj = idx & (SW - 1);
    const int j = j0 + jj;
    const int g = g_s[idx];
    int best = g * g;
    for (int r = 1; r * r < best; ++r) {
      const int im = i - r, ip = i + r;
      if (im >= 0) { const int v = g_s[im * SW + jj]; best = min(best, r * r + v * v); }
      if (ip < HH) { const int v = g_s[ip * SW + jj]; best = min(best, r * r + v * v); }
    }
    const float dist = sqrtf((float)best);   // integer < 2^24: exact
    const float x = lg[i * WW + j];
    const float p = 1.0f / (1.0f + expf(-x));
    const float t = (float)gt[i * WW + j];
    acc += fabsf(p - t) * dist;
  }

  // ---- Block reduction -> one atomic per block ----
  __shared__ float red[THREADS / 64];
  for (int off = 32; off > 0; off >>= 1) acc += __shfl_down(acc, off, 64);
  const int lane = threadIdx.x & 63;
  const int wid = threadIdx.x >> 6;
  if (lane == 0) red[wid] = acc;
  __syncthreads();
  if (threadIdx.x == 0) {
    float s = 0.0f;
    for (int w = 0; w < THREADS / 64; ++w) s += red[w];
    atomicAdd(out, s * (1.0f / (float)(BB * HH * WW)));
  }
}

extern "C" void kernel_launch(void* const* d_in, const int* in_sizes, int n_in,
                              void* d_out, int out_size, void* d_ws, size_t ws_size,
                              hipStream_t stream) {
  const float* logits = (const float*)d_in[0];
  const int* targets = (const int*)d_in[1];
  float* out = (float*)d_out;
  unsigned* mask = (unsigned*)d_ws;  // 16*384*384/32 u32 = 294912 B

  hipMemsetAsync(d_out, 0, sizeof(float), stream);
  pack_kernel<<<(BB * HH * WW) / THREADS, THREADS, 0, stream>>>(targets, mask);
  boundary_loss_kernel<<<BB * NBLK_PER_IMG, THREADS, 0, stream>>>(logits, targets, mask, out);
}

// Round 3
// 82.281 us; speedup vs baseline: 1.5908x; 1.0923x over previous
//
#include <hip/hip_runtime.h>
#include <math.h>

// BoundaryLoss: out = mean |sigmoid(logits) - gt| * EDT_bg(gt)
// Key identity: dist==0 exactly at gt==1, so |p-t|*dist == p*dist -> targets
// only needed to build the fg bitmask.
// Kernel 1: pack gt!=0 bitmask into d_ws (+ zero d_out).
// Kernel 2: per 8-col stripe: stage bitmask to LDS, clz/ffs row distances,
//           early-exit exact vertical envelope, fused sigmoid*dist reduction.

#define BB 16
#define HH 384
#define WW 384
#define WPR 12                 // u32 words per row
#define WPRP 13                // padded LDS stride (coprime 32: conflict-free)
#define SW 8                   // stripe width
#define NBLK (WW / SW)         // 48
#define THREADS 256
#define BIGD 768

__global__ __launch_bounds__(THREADS) void pack_kernel(
    const int* __restrict__ gt, unsigned* __restrict__ mask,
    float* __restrict__ out) {
  const int idx = blockIdx.x * THREADS + threadIdx.x;
  const bool fg = gt[idx] != 0;
  const unsigned long long m = __ballot(fg);
  const int lane = threadIdx.x & 63;
  if (lane == 0) mask[idx >> 5] = (unsigned)m;
  else if (lane == 32) mask[idx >> 5] = (unsigned)(m >> 32);
  if (idx == 0) out[0] = 0.0f;
}

__global__ __launch_bounds__(THREADS) void boundary_loss_kernel(
    const float* __restrict__ logits, const unsigned* __restrict__ mask,
    float* __restrict__ out) {
  const int blk = blockIdx.x;
  const int b = blk / NBLK;
  const int j0 = (blk % NBLK) * SW;
  const float* __restrict__ lg = logits + b * HH * WW;

  __shared__ unsigned m_s[HH * WPRP];       // 19968 B
  __shared__ unsigned short g_s[HH * SW];   // 6144 B

  // ---- stage fg bitmask: uint4 global loads, scalar LDS writes (padded) ----
  const uint4* __restrict__ gm4 = (const uint4*)(mask + b * HH * WPR);
  for (int s = threadIdx.x; s < HH * WPR / 4; s += THREADS) {  // 1152
    const uint4 v = gm4[s];
    const int row = s / 3;                  // 3 uint4 per row
    const int w0 = (s - row * 3) * 4;
    unsigned* dst = m_s + row * WPRP + w0;
    dst[0] = v.x; dst[1] = v.y; dst[2] = v.z; dst[3] = v.w;
  }
  __syncthreads();

  // ---- Phase 1: exact nearest-fg row distance, 4 cols/thread, shared walks ----
  for (int s = threadIdx.x; s < HH * 2; s += THREADS) {        // 3 iters
    const int i = s >> 1;
    const int jj = (s & 1) * 4;
    const int j = j0 + jj;                  // j % 4 == 0 -> 4 bits in one word
    const unsigned* __restrict__ mr = m_s + i * WPRP;
    const int w = j >> 5;
    const int bpos = j & 31;                // <= 28
    const unsigned cur = mr[w];

    int jL = -0x40000;                      // nearest fg strictly left of word w
    if ((cur & (0xFFFFFFFFu >> (31 - bpos))) == 0u) {  // only col0's mask empty matters
      for (int ww = w - 1; ww >= 0; --ww) {
        const unsigned x = mr[ww];
        if (x) { jL = ww * 32 + 31 - __clz(x); break; }
      }
    }
    int jR = 0x40000;                       // nearest fg strictly right of word w
    if ((cur & (0xFFFFFFFFu << (bpos + 3))) == 0u) {   // only col3's mask empty matters
      for (int ww = w + 1; ww < WPR; ++ww) {
        const unsigned x = mr[ww];
        if (x) { jR = ww * 32 + __ffs(x) - 1; break; }
      }
    }
    unsigned short g4[4];
#pragma unroll
    for (int c = 0; c < 4; ++c) {
      const int bc = bpos + c;
      const int jc = j + c;
      const unsigned lm = cur & (0xFFFFFFFFu >> (31 - bc));
      const unsigned rm = cur & (0xFFFFFFFFu << bc);
      const int dl = lm ? (bc - (31 - __clz(lm))) : (jc - jL);
      const int dr = rm ? ((__ffs(rm) - 1) - bc) : (jR - jc);
      g4[c] = (unsigned short)min(min(dl, dr), BIGD);
    }
    ushort4 gv; gv.x = g4[0]; gv.y = g4[1]; gv.z = g4[2]; gv.w = g4[3];
    *(ushort4*)(g_s + i * SW + jj) = gv;    // 8B-aligned
  }
  __syncthreads();

  // ---- Phase 2: exact vertical envelope (early exit r*r >= best) + loss ----
  float acc = 0.0f;
  for (int s = threadIdx.x; s < HH * 2; s += THREADS) {
    const int i = s >> 1;
    const int jj = (s & 1) * 4;
    const ushort4 gv = *(const ushort4*)(g_s + i * SW + jj);
    const float4 x4 = *(const float4*)(lg + i * WW + j0 + jj);
    const int gg[4] = {gv.x, gv.y, gv.z, gv.w};
    const float xs[4] = {x4.x, x4.y, x4.z, x4.w};
#pragma unroll
    for (int c = 0; c < 4; ++c) {
      int best = gg[c] * gg[c];
      for (int r = 1; r * r < best; ++r) {
        const int im = i - r, ip = i + r;
        if (im >= 0) { const int v = g_s[im * SW + jj + c]; best = min(best, r * r + v * v); }
        if (ip < HH) { const int v = g_s[ip * SW + jj + c]; best = min(best, r * r + v * v); }
      }
      const float dist = sqrtf((float)best);        // integer < 2^24: exact
      const float p = 1.0f / (1.0f + __expf(-xs[c]));
      acc += p * dist;                               // == |p-t|*dist (dist=0 at fg)
    }
  }

  // ---- Block reduction -> one atomic per block ----
  __shared__ float red[THREADS / 64];
  for (int off = 32; off > 0; off >>= 1) acc += __shfl_down(acc, off, 64);
  const int lane = threadIdx.x & 63;
  const int wid = threadIdx.x >> 6;
  if (lane == 0) red[wid] = acc;
  __syncthreads();
  if (threadIdx.x == 0) {
    float ssum = 0.0f;
    for (int w = 0; w < THREADS / 64; ++w) ssum += red[w];
    atomicAdd(out, ssum * (1.0f / (float)(BB * HH * WW)));
  }
}

extern "C" void kernel_launch(void* const* d_in, const int* in_sizes, int n_in,
                              void* d_out, int out_size, void* d_ws, size_t ws_size,
                              hipStream_t stream) {
  const float* logits = (const float*)d_in[0];
  const int* targets = (const int*)d_in[1];
  float* out = (float*)d_out;
  unsigned* mask = (unsigned*)d_ws;       // 16*384*384/32 u32 = 294912 B

  pack_kernel<<<(BB * HH * WW) / THREADS, THREADS, 0, stream>>>(targets, mask, out);
  boundary_loss_kernel<<<BB * NBLK, THREADS, 0, stream>>>(logits, mask, out);
}

// Round 4
// 75.504 us; speedup vs baseline: 1.7337x; 1.0898x over previous
//
#include <hip/hip_runtime.h>
#include <math.h>

// BoundaryLoss: out = mean |sigmoid(logits) - gt| * EDT_bg(gt)
// dist==0 exactly at gt==1  ->  |p-t|*dist == p*dist: targets only feed the
// fg bitmask.
// K1 pack: 8 px/thread -> fg byte -> LDS -> u32 word stores (+ zero d_out).
// K2 main: per 16-col stripe: bitmask -> LDS, clz/ffs exact row distances,
//          early-exit exact vertical envelope, fused sigmoid*dist reduce.

#define BB 16
#define HH 384
#define WW 384
#define WPR 12                 // u32 words per row
#define WPRP 13                // padded LDS stride (coprime 32: conflict-free)
#define SW 16                  // stripe width
#define NBLK (WW / SW)         // 24
#define THREADS 512
#define PTHREADS 256
#define BIGD 768

__global__ __launch_bounds__(PTHREADS) void pack_kernel(
    const int* __restrict__ gt, unsigned* __restrict__ mask,
    float* __restrict__ out) {
  __shared__ unsigned char s_byte[PTHREADS];
  const int base = blockIdx.x * PTHREADS * 8;        // 2048 px per block
  const int4* __restrict__ g4 = (const int4*)(gt + base);
  const int4 a = g4[threadIdx.x * 2];
  const int4 b = g4[threadIdx.x * 2 + 1];
  unsigned byte = (a.x != 0) | ((a.y != 0) << 1) | ((a.z != 0) << 2) |
                  ((a.w != 0) << 3) | ((b.x != 0) << 4) | ((b.y != 0) << 5) |
                  ((b.z != 0) << 6) | ((b.w != 0) << 7);
  s_byte[threadIdx.x] = (unsigned char)byte;
  __syncthreads();
  if (threadIdx.x < PTHREADS / 4) {                  // 64 word stores
    mask[(base >> 5) + threadIdx.x] = *(const unsigned*)(s_byte + threadIdx.x * 4);
  }
  if (blockIdx.x == 0 && threadIdx.x == 0) out[0] = 0.0f;
}

__global__ __launch_bounds__(THREADS) void boundary_loss_kernel(
    const float* __restrict__ logits, const unsigned* __restrict__ mask,
    float* __restrict__ out) {
  const int blk = blockIdx.x;
  const int b = blk / NBLK;
  const int j0 = (blk % NBLK) * SW;
  const float* __restrict__ lg = logits + b * HH * WW;

  __shared__ unsigned m_s[HH * WPRP];       // 19968 B
  __shared__ unsigned short g_s[HH * SW];   // 12288 B

  // ---- stage fg bitmask: uint4 global loads, scalar LDS writes (padded) ----
  const uint4* __restrict__ gm4 = (const uint4*)(mask + b * HH * WPR);
  for (int s = threadIdx.x; s < HH * WPR / 4; s += THREADS) {  // 1152
    const uint4 v = gm4[s];
    const int row = s / 3;
    const int w0 = (s - row * 3) * 4;
    unsigned* dst = m_s + row * WPRP + w0;
    dst[0] = v.x; dst[1] = v.y; dst[2] = v.z; dst[3] = v.w;
  }
  __syncthreads();

  // ---- Phase 1: exact nearest-fg row distance, 4 cols/thread ----
  for (int s = threadIdx.x; s < HH * (SW / 4); s += THREADS) {  // 1536 / 512 = 3
    const int i = s >> 2;
    const int jj = (s & 3) * 4;
    const int j = j0 + jj;                  // multiple of 4: 4 bits in one word
    const unsigned* __restrict__ mr = m_s + i * WPRP;
    const int w = j >> 5;
    const int bpos = j & 31;                // 0,4,...,28
    const unsigned cur = mr[w];

    int jL = -0x40000;
    if ((cur & (0xFFFFFFFFu >> (31 - bpos))) == 0u) {
      for (int ww = w - 1; ww >= 0; --ww) {
        const unsigned x = mr[ww];
        if (x) { jL = ww * 32 + 31 - __clz(x); break; }
      }
    }
    int jR = 0x40000;
    if ((cur & (0xFFFFFFFFu << (bpos + 3))) == 0u) {
      for (int ww = w + 1; ww < WPR; ++ww) {
        const unsigned x = mr[ww];
        if (x) { jR = ww * 32 + __ffs(x) - 1; break; }
      }
    }
    unsigned short g4[4];
#pragma unroll
    for (int c = 0; c < 4; ++c) {
      const int bc = bpos + c;
      const int jc = j + c;
      const unsigned lm = cur & (0xFFFFFFFFu >> (31 - bc));
      const unsigned rm = cur & (0xFFFFFFFFu << bc);
      const int dl = lm ? (bc - (31 - __clz(lm))) : (jc - jL);
      const int dr = rm ? ((__ffs(rm) - 1) - bc) : (jR - jc);
      g4[c] = (unsigned short)min(min(dl, dr), BIGD);
    }
    ushort4 gv; gv.x = g4[0]; gv.y = g4[1]; gv.z = g4[2]; gv.w = g4[3];
    *(ushort4*)(g_s + i * SW + jj) = gv;
  }
  __syncthreads();

  // ---- Phase 2: exact vertical envelope (early exit r*r >= best) + loss ----
  float acc = 0.0f;
  for (int s = threadIdx.x; s < HH * (SW / 4); s += THREADS) {
    const int i = s >> 2;
    const int jj = (s & 3) * 4;
    const ushort4 gv = *(const ushort4*)(g_s + i * SW + jj);
    const float4 x4 = *(const float4*)(lg + i * WW + j0 + jj);
    const int gg[4] = {gv.x, gv.y, gv.z, gv.w};
    const float xs[4] = {x4.x, x4.y, x4.z, x4.w};
#pragma unroll
    for (int c = 0; c < 4; ++c) {
      int best = gg[c] * gg[c];
      for (int r = 1; r * r < best; ++r) {
        const int im = i - r, ip = i + r;
        if (im >= 0) { const int v = g_s[im * SW + jj + c]; best = min(best, r * r + v * v); }
        if (ip < HH) { const int v = g_s[ip * SW + jj + c]; best = min(best, r * r + v * v); }
      }
      const float dist = __builtin_amdgcn_sqrtf((float)best);     // rel ~1e-7
      const float p = __builtin_amdgcn_rcpf(1.0f + __expf(-xs[c])); // rel ~2.5e-7
      acc += p * dist;                        // == |p-t|*dist (dist=0 at fg)
    }
  }

  // ---- Block reduction -> one fire-and-forget atomic per block ----
  __shared__ float red[THREADS / 64];
  for (int off = 32; off > 0; off >>= 1) acc += __shfl_down(acc, off, 64);
  const int lane = threadIdx.x & 63;
  const int wid = threadIdx.x >> 6;
  if (lane == 0) red[wid] = acc;
  __syncthreads();
  if (threadIdx.x == 0) {
    float ssum = 0.0f;
    for (int w = 0; w < THREADS / 64; ++w) ssum += red[w];
    atomicAdd(out, ssum * (1.0f / (float)(BB * HH * WW)));
  }
}

extern "C" void kernel_launch(void* const* d_in, const int* in_sizes, int n_in,
                              void* d_out, int out_size, void* d_ws, size_t ws_size,
                              hipStream_t stream) {
  const float* logits = (const float*)d_in[0];
  const int* targets = (const int*)d_in[1];
  float* out = (float*)d_out;
  unsigned* mask = (unsigned*)d_ws;       // 294912 B

  pack_kernel<<<(BB * HH * WW) / (PTHREADS * 8), PTHREADS, 0, stream>>>(targets, mask, out);
  boundary_loss_kernel<<<BB * NBLK, THREADS, 0, stream>>>(logits, mask, out);
}